// Round 1
// baseline (11064.726 us; speedup 1.0000x reference)
//
#include <hip/hip_runtime.h>
#include <math.h>

// Problem constants (fixed by the reference)
constexpr int V  = 32000;
constexpr int T  = 2048;
constexpr int E  = 1024;
constexpr int H  = 16;
constexpr int FF = 4096;
constexpr int L  = 4;
constexpr int B  = 2;
constexpr int C  = 1024;
constexpr int D  = 64;          // head dim
constexpr int N  = B * C;       // 2048 tokens
constexpr float EPS = 1e-5f;

// ---------------------------------------------------------------------------
// Embedding: h[token] = embed[x[token]] + pos_embed[token % C]
// ---------------------------------------------------------------------------
__global__ void embed_kernel(const int* __restrict__ x,
                             const float* __restrict__ embed,
                             const float* __restrict__ pos,
                             float* __restrict__ h) {
    int token = blockIdx.x;          // 0..N-1
    int c = token % C;               // position (C <= T so clip is identity)
    int id = x[token];
    const float* erow = embed + (size_t)id * E;
    const float* prow = pos   + (size_t)c  * E;
    float* hrow = h + (size_t)token * E;
    for (int e = threadIdx.x; e < E; e += blockDim.x)
        hrow[e] = erow[e] + prow[e];
}

// ---------------------------------------------------------------------------
// LayerNorm: one 256-thread block per token row (E=1024 -> 4 elems/thread)
// ---------------------------------------------------------------------------
__global__ void layernorm_kernel(const float* __restrict__ in,
                                 const float* __restrict__ w,
                                 const float* __restrict__ b,
                                 float* __restrict__ out) {
    __shared__ float red[256];
    int token = blockIdx.x;
    int tid = threadIdx.x;
    const float* row = in + (size_t)token * E;
    float x0 = row[tid];
    float x1 = row[tid + 256];
    float x2 = row[tid + 512];
    float x3 = row[tid + 768];

    red[tid] = x0 + x1 + x2 + x3;
    __syncthreads();
    for (int st = 128; st > 0; st >>= 1) {
        if (tid < st) red[tid] += red[tid + st];
        __syncthreads();
    }
    float mu = red[0] * (1.0f / E);
    __syncthreads();

    float d0 = x0 - mu, d1 = x1 - mu, d2 = x2 - mu, d3 = x3 - mu;
    red[tid] = d0 * d0 + d1 * d1 + d2 * d2 + d3 * d3;
    __syncthreads();
    for (int st = 128; st > 0; st >>= 1) {
        if (tid < st) red[tid] += red[tid + st];
        __syncthreads();
    }
    float var = red[0] * (1.0f / E);
    float inv = rsqrtf(var + EPS);

    float* orow = out + (size_t)token * E;
    orow[tid]       = d0 * inv * w[tid]       + b[tid];
    orow[tid + 256] = d1 * inv * w[tid + 256] + b[tid + 256];
    orow[tid + 512] = d2 * inv * w[tid + 512] + b[tid + 512];
    orow[tid + 768] = d3 * inv * w[tid + 768] + b[tid + 768];
}

// ---------------------------------------------------------------------------
// Causal attention, one block per (q, head, batch).
// Q/K/V/O layout: [B, C, H, D] flattened as [N, E] with column = h*D + d.
// ---------------------------------------------------------------------------
__global__ void attention_kernel(const float* __restrict__ Q,
                                 const float* __restrict__ K,
                                 const float* __restrict__ Vm,
                                 float* __restrict__ O) {
    int qi = blockIdx.x;   // query position 0..C-1
    int hh = blockIdx.y;   // head
    int bb = blockIdx.z;   // batch
    int tid = threadIdx.x; // 256 threads

    __shared__ float sQ[D];
    __shared__ float sS[C];
    __shared__ float red[256];

    if (tid < D)
        sQ[tid] = Q[(size_t)(bb * C + qi) * E + hh * D + tid];
    __syncthreads();

    const float scale = 0.125f; // 1/sqrt(64)

    // scores + local max
    float lmax = -INFINITY;
    for (int k = tid; k <= qi; k += 256) {
        const float* krow = K + (size_t)(bb * C + k) * E + hh * D;
        float dot = 0.f;
        #pragma unroll
        for (int d = 0; d < D; ++d) dot += sQ[d] * krow[d];
        dot *= scale;
        sS[k] = dot;
        lmax = fmaxf(lmax, dot);
    }
    red[tid] = lmax;
    __syncthreads();
    for (int st = 128; st > 0; st >>= 1) {
        if (tid < st) red[tid] = fmaxf(red[tid], red[tid + st]);
        __syncthreads();
    }
    float m = red[0];
    __syncthreads();

    // exp + local sum
    float lsum = 0.f;
    for (int k = tid; k <= qi; k += 256) {
        float e = expf(sS[k] - m);
        sS[k] = e;
        lsum += e;
    }
    red[tid] = lsum;
    __syncthreads();
    for (int st = 128; st > 0; st >>= 1) {
        if (tid < st) red[tid] += red[tid + st];
        __syncthreads();
    }
    float inv = 1.0f / red[0];
    __syncthreads();

    // weighted sum of V: 4 k-groups x 64 dims
    int d = tid & 63;
    int g = tid >> 6;
    float acc = 0.f;
    for (int k = g; k <= qi; k += 4)
        acc += sS[k] * Vm[(size_t)(bb * C + k) * E + hh * D + d];
    red[tid] = acc;
    __syncthreads();
    if (g == 0) {
        float tot = red[d] + red[64 + d] + red[128 + d] + red[192 + d];
        O[(size_t)(bb * C + qi) * E + hh * D + d] = tot * inv;
    }
}

// ---------------------------------------------------------------------------
// Tiled f32 GEMM: Cm = [res +] epilogue(A @ Bm [+ bias])
// A: [M,K] row-major, Bm: [K,Nc] row-major, Cm: [M,Nc].
// Tile 64x64, 256 threads (16x16), each thread a 4x4 microtile, K-tile 16.
// gelu_flag: apply exact-erf GELU after bias, before residual.
// All of M, Nc % 64 == 0 and K % 16 == 0 for this problem.
// ---------------------------------------------------------------------------
#define BT 64
#define KT 16
__launch_bounds__(256)
__global__ void gemm_ep(const float* __restrict__ A,
                        const float* __restrict__ Bm,
                        const float* __restrict__ bias,
                        const float* __restrict__ res,
                        float* __restrict__ Cm,
                        int M, int Nc, int K, int gelu_flag) {
    __shared__ float As[KT][BT + 1];  // +1 pad: conflict-free writes
    __shared__ float Bs[KT][BT];

    int tid = threadIdx.x;        // 0..255
    int tx = tid & 15;            // col group
    int ty = tid >> 4;            // row group
    int row0 = blockIdx.y * BT;
    int col0 = blockIdx.x * BT;

    float acc[4][4] = {};

    for (int k0 = 0; k0 < K; k0 += KT) {
        #pragma unroll
        for (int t = 0; t < 4; ++t) {
            int idx = tid + t * 256;          // 0..1023
            int kk = idx & 15, mm = idx >> 4; // A: 64 rows x 16 k
            As[kk][mm] = A[(size_t)(row0 + mm) * K + k0 + kk];
        }
        #pragma unroll
        for (int t = 0; t < 4; ++t) {
            int idx = tid + t * 256;
            int nn = idx & 63, kk = idx >> 6; // B: 16 k x 64 cols
            Bs[kk][nn] = Bm[(size_t)(k0 + kk) * Nc + col0 + nn];
        }
        __syncthreads();

        #pragma unroll
        for (int kk = 0; kk < KT; ++kk) {
            float a[4], bv[4];
            #pragma unroll
            for (int i = 0; i < 4; ++i) a[i] = As[kk][ty + 16 * i];
            #pragma unroll
            for (int j = 0; j < 4; ++j) bv[j] = Bs[kk][tx + 16 * j];
            #pragma unroll
            for (int i = 0; i < 4; ++i)
                #pragma unroll
                for (int j = 0; j < 4; ++j)
                    acc[i][j] += a[i] * bv[j];
        }
        __syncthreads();
    }

    #pragma unroll
    for (int i = 0; i < 4; ++i) {
        int r = row0 + ty + 16 * i;
        #pragma unroll
        for (int j = 0; j < 4; ++j) {
            int cc = col0 + tx + 16 * j;
            float val = acc[i][j];
            if (bias) val += bias[cc];
            if (gelu_flag) val = 0.5f * val * (1.0f + erff(val * 0.70710678118f));
            if (res) val += res[(size_t)r * Nc + cc];
            Cm[(size_t)r * Nc + cc] = val;
        }
    }
}

// ---------------------------------------------------------------------------
extern "C" void kernel_launch(void* const* d_in, const int* in_sizes, int n_in,
                              void* d_out, int out_size, void* d_ws, size_t ws_size,
                              hipStream_t stream) {
    const int*   x     = (const int*)  d_in[0];
    const float* embed = (const float*)d_in[1];
    const float* pos   = (const float*)d_in[2];
    const float* Wq    = (const float*)d_in[3];
    const float* Wk    = (const float*)d_in[4];
    const float* Wv    = (const float*)d_in[5];
    const float* Wo    = (const float*)d_in[6];
    const float* ln1w  = (const float*)d_in[7];
    const float* ln1b  = (const float*)d_in[8];
    const float* ln2w  = (const float*)d_in[9];
    const float* ln2b  = (const float*)d_in[10];
    const float* W1    = (const float*)d_in[11];
    const float* b1    = (const float*)d_in[12];
    const float* W2    = (const float*)d_in[13];
    const float* b2    = (const float*)d_in[14];
    const float* lnfw  = (const float*)d_in[15];
    const float* lnfb  = (const float*)d_in[16];
    const float* Wout  = (const float*)d_in[17];
    const float* bout  = (const float*)d_in[18];
    float* out = (float*)d_out;

    // workspace layout (f32): 6 * N*E + N*FF = ~84 MB
    float* ws   = (float*)d_ws;
    float* h    = ws;
    float* hn   = h    + (size_t)N * E;
    float* q    = hn   + (size_t)N * E;
    float* k    = q    + (size_t)N * E;
    float* v    = k    + (size_t)N * E;
    float* attn = v    + (size_t)N * E;
    float* ff   = attn + (size_t)N * E;

    embed_kernel<<<N, 256, 0, stream>>>(x, embed, pos, h);

    dim3 gridE(E / BT, N / BT);    // (16, 32)
    dim3 gridF(FF / BT, N / BT);   // (64, 32)
    dim3 gridV(V / BT, N / BT);    // (500, 32)

    for (int i = 0; i < L; ++i) {
        layernorm_kernel<<<N, 256, 0, stream>>>(h, ln1w + i * E, ln1b + i * E, hn);

        gemm_ep<<<gridE, 256, 0, stream>>>(hn, Wq + (size_t)i * E * E, nullptr, nullptr, q, N, E, E, 0);
        gemm_ep<<<gridE, 256, 0, stream>>>(hn, Wk + (size_t)i * E * E, nullptr, nullptr, k, N, E, E, 0);
        gemm_ep<<<gridE, 256, 0, stream>>>(hn, Wv + (size_t)i * E * E, nullptr, nullptr, v, N, E, E, 0);

        attention_kernel<<<dim3(C, H, B), 256, 0, stream>>>(q, k, v, attn);

        // h = h + attn @ Wo
        gemm_ep<<<gridE, 256, 0, stream>>>(attn, Wo + (size_t)i * E * E, nullptr, h, h, N, E, E, 0);

        layernorm_kernel<<<N, 256, 0, stream>>>(h, ln2w + i * E, ln2b + i * E, hn);

        // ff = gelu(hn @ W1 + b1)
        gemm_ep<<<gridF, 256, 0, stream>>>(hn, W1 + (size_t)i * E * FF, b1 + i * FF, nullptr, ff, N, FF, E, 1);
        // h = h + ff @ W2 + b2
        gemm_ep<<<gridE, 256, 0, stream>>>(ff, W2 + (size_t)i * FF * E, b2 + i * E, h, h, N, E, FF, 0);
    }

    layernorm_kernel<<<N, 256, 0, stream>>>(h, lnfw, lnfb, hn);
    // out = hn @ Wout + bout
    gemm_ep<<<gridV, 256, 0, stream>>>(hn, Wout, bout, nullptr, out, N, V, E, 0);
}

// Round 2
// 5288.910 us; speedup vs baseline: 2.0921x; 2.0921x over previous
//
#include <hip/hip_runtime.h>
#include <hip/hip_bf16.h>
#include <math.h>

// Problem constants
constexpr int V  = 32000;
constexpr int E  = 1024;
constexpr int H  = 16;
constexpr int FF = 4096;
constexpr int L  = 4;
constexpr int B  = 2;
constexpr int C  = 1024;
constexpr int D  = 64;
constexpr int N  = B * C;        // 2048 tokens
constexpr int E3 = 3 * E;        // packed QKV width
constexpr float EPS = 1e-5f;

typedef __hip_bfloat16 bf16;
typedef __bf16 bf16x8 __attribute__((ext_vector_type(8)));
typedef float  f32x4  __attribute__((ext_vector_type(4)));

// ---------------------------------------------------------------------------
// Embedding: h[token] = embed[x[token]] + pos_embed[token % C]   (f32 out)
// ---------------------------------------------------------------------------
__global__ void embed_kernel(const int* __restrict__ x,
                             const float* __restrict__ embed,
                             const float* __restrict__ pos,
                             float* __restrict__ h) {
    int token = blockIdx.x;
    int c = token % C;
    int id = x[token];
    const float* erow = embed + (size_t)id * E;
    const float* prow = pos   + (size_t)c  * E;
    float* hrow = h + (size_t)token * E;
    for (int e = threadIdx.x; e < E; e += blockDim.x)
        hrow[e] = erow[e] + prow[e];
}

// ---------------------------------------------------------------------------
// LayerNorm: f32 in -> bf16 out. One 256-thread block per token.
// ---------------------------------------------------------------------------
__global__ void layernorm_kernel(const float* __restrict__ in,
                                 const float* __restrict__ w,
                                 const float* __restrict__ b,
                                 bf16* __restrict__ out) {
    __shared__ float red[256];
    int token = blockIdx.x;
    int tid = threadIdx.x;
    const float* row = in + (size_t)token * E;
    float x0 = row[tid];
    float x1 = row[tid + 256];
    float x2 = row[tid + 512];
    float x3 = row[tid + 768];

    red[tid] = x0 + x1 + x2 + x3;
    __syncthreads();
    for (int st = 128; st > 0; st >>= 1) {
        if (tid < st) red[tid] += red[tid + st];
        __syncthreads();
    }
    float mu = red[0] * (1.0f / E);
    __syncthreads();

    float d0 = x0 - mu, d1 = x1 - mu, d2 = x2 - mu, d3 = x3 - mu;
    red[tid] = d0 * d0 + d1 * d1 + d2 * d2 + d3 * d3;
    __syncthreads();
    for (int st = 128; st > 0; st >>= 1) {
        if (tid < st) red[tid] += red[tid + st];
        __syncthreads();
    }
    float var = red[0] * (1.0f / E);
    float inv = rsqrtf(var + EPS);

    bf16* orow = out + (size_t)token * E;
    orow[tid]       = __float2bfloat16(d0 * inv * w[tid]       + b[tid]);
    orow[tid + 256] = __float2bfloat16(d1 * inv * w[tid + 256] + b[tid + 256]);
    orow[tid + 512] = __float2bfloat16(d2 * inv * w[tid + 512] + b[tid + 512]);
    orow[tid + 768] = __float2bfloat16(d3 * inv * w[tid + 768] + b[tid + 768]);
}

// ---------------------------------------------------------------------------
// Weight convert+transpose: in f32 [K,N] -> out bf16 [N,K].
// 256 threads = 32x8, 32x32 tile via LDS.
// ---------------------------------------------------------------------------
__global__ void transpose_bf16(const float* __restrict__ in,
                               bf16* __restrict__ out, int K, int Nn) {
    __shared__ float tile[32][33];
    int n0 = blockIdx.x * 32, k0 = blockIdx.y * 32;
    int tx = threadIdx.x & 31, ty = threadIdx.x >> 5;   // 32 x 8
    #pragma unroll
    for (int i = 0; i < 32; i += 8)
        tile[ty + i][tx] = in[(size_t)(k0 + ty + i) * Nn + n0 + tx];
    __syncthreads();
    #pragma unroll
    for (int i = 0; i < 32; i += 8)
        out[(size_t)(n0 + ty + i) * K + k0 + tx] = __float2bfloat16(tile[tx][ty + i]);
}

// ---------------------------------------------------------------------------
// bf16 MFMA GEMM (m97 structure): C = [res +] ep(A @ Bt^T [+ bias])
// A: [M,K] bf16 row-major. Bt: [Nc,K] bf16 row-major (pre-transposed).
// 128x128 tile, 4 waves (2x2), each wave 64x64 via 4x4 frags of 16x16x32.
// BK=32, single LDS buffer, global_load_lds width 16.
// ---------------------------------------------------------------------------
constexpr int GBM = 128, GBN = 128, GBK = 32;

__launch_bounds__(256)
__global__ void gemm_bf16(const bf16* __restrict__ A,
                          const bf16* __restrict__ Bt,
                          const float* __restrict__ bias,
                          const float* __restrict__ res,
                          float* __restrict__ outF,
                          bf16*  __restrict__ outB,
                          int M, int Nc, int K, int gelu_flag) {
    __shared__ __align__(16) bf16 As[GBM * GBK];   // 8 KB
    __shared__ __align__(16) bf16 Bs[GBN * GBK];   // 8 KB

    int tid  = threadIdx.x;
    int lane = tid & 63;
    int wid  = tid >> 6;          // 0..3
    int wr   = wid >> 1;          // wave row (0..1)
    int wc   = wid & 1;           // wave col (0..1)

    size_t brow = (size_t)blockIdx.y * GBM;
    size_t bcol = (size_t)blockIdx.x * GBN;

    f32x4 acc[4][4] = {};

    for (int k0 = 0; k0 < K; k0 += GBK) {
        // ---- stage A,B tiles: 512 slots of 16B each (8 bf16), 2 per thread
        #pragma unroll
        for (int it = 0; it < 2; ++it) {
            int sbase = (wid * 2 + it) * 64;       // wave-uniform slot base
            int s = sbase + lane;                  // this lane's slot
            const bf16* ga = A  + (brow + (s >> 2)) * K + k0 + (s & 3) * 8;
            const bf16* gb = Bt + (bcol + (s >> 2)) * K + k0 + (s & 3) * 8;
            __builtin_amdgcn_global_load_lds(
                (const __attribute__((address_space(1))) void*)ga,
                (__attribute__((address_space(3))) void*)(As + (size_t)sbase * 8),
                16, 0, 0);
            __builtin_amdgcn_global_load_lds(
                (const __attribute__((address_space(1))) void*)gb,
                (__attribute__((address_space(3))) void*)(Bs + (size_t)sbase * 8),
                16, 0, 0);
        }
        __syncthreads();

        // ---- fragments + MFMA
        bf16x8 af[4], bfr[4];
        int klo = (lane >> 4) * 8;       // k sub-offset within BK
        int rsub = lane & 15;
        #pragma unroll
        for (int m = 0; m < 4; ++m) {
            int row = wr * 64 + m * 16 + rsub;
            af[m] = *(const bf16x8*)(As + row * GBK + klo);
        }
        #pragma unroll
        for (int n = 0; n < 4; ++n) {
            int row = wc * 64 + n * 16 + rsub;
            bfr[n] = *(const bf16x8*)(Bs + row * GBK + klo);
        }
        #pragma unroll
        for (int m = 0; m < 4; ++m)
            #pragma unroll
            for (int n = 0; n < 4; ++n)
                acc[m][n] = __builtin_amdgcn_mfma_f32_16x16x32_bf16(
                    af[m], bfr[n], acc[m][n], 0, 0, 0);
        __syncthreads();
    }

    // ---- epilogue: C/D layout col=lane&15, row=(lane>>4)*4+reg
    int crow = (lane >> 4) * 4;
    int ccol = lane & 15;
    #pragma unroll
    for (int m = 0; m < 4; ++m) {
        #pragma unroll
        for (int n = 0; n < 4; ++n) {
            #pragma unroll
            for (int r = 0; r < 4; ++r) {
                size_t row = brow + wr * 64 + m * 16 + crow + r;
                size_t col = bcol + wc * 64 + n * 16 + ccol;
                float val = acc[m][n][r];
                if (bias) val += bias[col];
                if (gelu_flag) val = 0.5f * val * (1.0f + erff(val * 0.70710678118f));
                if (res) val += res[row * Nc + col];
                if (outF) outF[row * Nc + col] = val;
                if (outB) outB[row * Nc + col] = __float2bfloat16(val);
            }
        }
    }
}

// ---------------------------------------------------------------------------
// Causal attention over packed QKV f32 [N, 3E]; output bf16 [N, E].
// One block per (q, head, batch).
// ---------------------------------------------------------------------------
__global__ void attention_kernel(const float* __restrict__ QKV,
                                 bf16* __restrict__ O) {
    int qi = blockIdx.x;
    int hh = blockIdx.y;
    int bb = blockIdx.z;
    int tid = threadIdx.x;

    __shared__ float sQ[D];
    __shared__ float sS[C];
    __shared__ float red[256];

    if (tid < D)
        sQ[tid] = QKV[(size_t)(bb * C + qi) * E3 + hh * D + tid];
    __syncthreads();

    const float scale = 0.125f;

    float lmax = -INFINITY;
    for (int k = tid; k <= qi; k += 256) {
        const float* krow = QKV + (size_t)(bb * C + k) * E3 + E + hh * D;
        float dot = 0.f;
        #pragma unroll
        for (int d = 0; d < D; ++d) dot += sQ[d] * krow[d];
        dot *= scale;
        sS[k] = dot;
        lmax = fmaxf(lmax, dot);
    }
    red[tid] = lmax;
    __syncthreads();
    for (int st = 128; st > 0; st >>= 1) {
        if (tid < st) red[tid] = fmaxf(red[tid], red[tid + st]);
        __syncthreads();
    }
    float m = red[0];
    __syncthreads();

    float lsum = 0.f;
    for (int k = tid; k <= qi; k += 256) {
        float e = expf(sS[k] - m);
        sS[k] = e;
        lsum += e;
    }
    red[tid] = lsum;
    __syncthreads();
    for (int st = 128; st > 0; st >>= 1) {
        if (tid < st) red[tid] += red[tid + st];
        __syncthreads();
    }
    float inv = 1.0f / red[0];
    __syncthreads();

    int d = tid & 63;
    int g = tid >> 6;
    float acc = 0.f;
    for (int k = g; k <= qi; k += 4)
        acc += sS[k] * QKV[(size_t)(bb * C + k) * E3 + 2 * E + hh * D + d];
    red[tid] = acc;
    __syncthreads();
    if (g == 0) {
        float tot = red[d] + red[64 + d] + red[128 + d] + red[192 + d];
        O[(size_t)(bb * C + qi) * E + hh * D + d] = __float2bfloat16(tot * inv);
    }
}

// ---------------------------------------------------------------------------
extern "C" void kernel_launch(void* const* d_in, const int* in_sizes, int n_in,
                              void* d_out, int out_size, void* d_ws, size_t ws_size,
                              hipStream_t stream) {
    const int*   x     = (const int*)  d_in[0];
    const float* embed = (const float*)d_in[1];
    const float* pos   = (const float*)d_in[2];
    const float* Wq    = (const float*)d_in[3];
    const float* Wk    = (const float*)d_in[4];
    const float* Wv    = (const float*)d_in[5];
    const float* Wo    = (const float*)d_in[6];
    const float* ln1w  = (const float*)d_in[7];
    const float* ln1b  = (const float*)d_in[8];
    const float* ln2w  = (const float*)d_in[9];
    const float* ln2b  = (const float*)d_in[10];
    const float* W1    = (const float*)d_in[11];
    const float* b1    = (const float*)d_in[12];
    const float* W2    = (const float*)d_in[13];
    const float* b2    = (const float*)d_in[14];
    const float* lnfw  = (const float*)d_in[15];
    const float* lnfb  = (const float*)d_in[16];
    const float* Wout  = (const float*)d_in[17];
    const float* bout  = (const float*)d_in[18];
    float* out = (float*)d_out;

    // ---- workspace carve-up
    char* p = (char*)d_ws;
    auto alloc = [&](size_t bytes) {
        char* r = p;
        p += (bytes + 255) & ~(size_t)255;
        return r;
    };
    float* h    = (float*)alloc((size_t)N * E  * 4);
    float* qkv  = (float*)alloc((size_t)N * E3 * 4);
    bf16*  hn   = (bf16*) alloc((size_t)N * E  * 2);
    bf16*  attn = (bf16*) alloc((size_t)N * E  * 2);
    bf16*  ff   = (bf16*) alloc((size_t)N * FF * 2);
    bf16*  qkvt = (bf16*) alloc((size_t)L * E3 * E * 2);   // [L][3E][E]
    bf16*  wot  = (bf16*) alloc((size_t)L * E  * E * 2);   // [L][E][E]
    bf16*  w1t  = (bf16*) alloc((size_t)L * FF * E * 2);   // [L][FF][E]
    bf16*  w2t  = (bf16*) alloc((size_t)L * E  * FF * 2);  // [L][E][FF]
    bf16*  wvt  = (bf16*) alloc((size_t)V * E  * 2);       // [V][E]

    // ---- weight convert+transpose (f32 [K,N] -> bf16 [N,K])
    for (int i = 0; i < L; ++i) {
        transpose_bf16<<<dim3(E / 32, E / 32), 256, 0, stream>>>(
            Wq + (size_t)i * E * E, qkvt + ((size_t)i * E3 + 0 * E) * E, E, E);
        transpose_bf16<<<dim3(E / 32, E / 32), 256, 0, stream>>>(
            Wk + (size_t)i * E * E, qkvt + ((size_t)i * E3 + 1 * E) * E, E, E);
        transpose_bf16<<<dim3(E / 32, E / 32), 256, 0, stream>>>(
            Wv + (size_t)i * E * E, qkvt + ((size_t)i * E3 + 2 * E) * E, E, E);
        transpose_bf16<<<dim3(E / 32, E / 32), 256, 0, stream>>>(
            Wo + (size_t)i * E * E, wot + (size_t)i * E * E, E, E);
        transpose_bf16<<<dim3(FF / 32, E / 32), 256, 0, stream>>>(
            W1 + (size_t)i * E * FF, w1t + (size_t)i * FF * E, E, FF);
        transpose_bf16<<<dim3(E / 32, FF / 32), 256, 0, stream>>>(
            W2 + (size_t)i * FF * E, w2t + (size_t)i * E * FF, FF, E);
    }
    transpose_bf16<<<dim3(V / 32, E / 32), 256, 0, stream>>>(Wout, wvt, E, V);

    embed_kernel<<<N, 256, 0, stream>>>(x, embed, pos, h);

    dim3 gQKV(E3 / GBN, N / GBM);   // (24, 16)
    dim3 gE  (E  / GBN, N / GBM);   // (8, 16)
    dim3 gF  (FF / GBN, N / GBM);   // (32, 16)
    dim3 gV  (V  / GBN, N / GBM);   // (250, 16)

    for (int i = 0; i < L; ++i) {
        layernorm_kernel<<<N, 256, 0, stream>>>(h, ln1w + i * E, ln1b + i * E, hn);

        // packed QKV = hn @ [Wq|Wk|Wv]   (f32 out for attention)
        gemm_bf16<<<gQKV, 256, 0, stream>>>(hn, qkvt + (size_t)i * E3 * E,
                                            nullptr, nullptr, qkv, nullptr,
                                            N, E3, E, 0);

        attention_kernel<<<dim3(C, H, B), 256, 0, stream>>>(qkv, attn);

        // h = h + attn @ Wo
        gemm_bf16<<<gE, 256, 0, stream>>>(attn, wot + (size_t)i * E * E,
                                          nullptr, h, h, nullptr,
                                          N, E, E, 0);

        layernorm_kernel<<<N, 256, 0, stream>>>(h, ln2w + i * E, ln2b + i * E, hn);

        // ff = gelu(hn @ W1 + b1)   (bf16 out)
        gemm_bf16<<<gF, 256, 0, stream>>>(hn, w1t + (size_t)i * FF * E,
                                          b1 + (size_t)i * FF, nullptr,
                                          nullptr, ff,
                                          N, FF, E, 1);
        // h = h + ff @ W2 + b2
        gemm_bf16<<<gE, 256, 0, stream>>>(ff, w2t + (size_t)i * E * FF,
                                          b2 + (size_t)i * E, h, h, nullptr,
                                          N, E, FF, 0);
    }

    layernorm_kernel<<<N, 256, 0, stream>>>(h, lnfw, lnfb, hn);
    // out = hn @ Wout + bout
    gemm_bf16<<<gV, 256, 0, stream>>>(hn, wvt, bout, nullptr, out, nullptr,
                                      N, V, E, 0);
}

// Round 3
// 1682.736 us; speedup vs baseline: 6.5754x; 3.1430x over previous
//
#include <hip/hip_runtime.h>
#include <hip/hip_bf16.h>
#include <math.h>

// Problem constants
constexpr int V  = 32000;
constexpr int E  = 1024;
constexpr int H  = 16;
constexpr int FF = 4096;
constexpr int L  = 4;
constexpr int B  = 2;
constexpr int C  = 1024;
constexpr int D  = 64;
constexpr int N  = B * C;        // 2048 tokens
constexpr int E3 = 3 * E;        // packed QKV width
constexpr float EPS = 1e-5f;

typedef __hip_bfloat16 bf16;
typedef __bf16 bf16x8 __attribute__((ext_vector_type(8)));
typedef __bf16 bf16x4 __attribute__((ext_vector_type(4)));
typedef float  f32x4  __attribute__((ext_vector_type(4)));

// 8-bf16 LDS load/store via two 8B ops (stride-72 rows are only 8B aligned)
__device__ inline bf16x8 lds_load8(const bf16* p) {
    bf16x4 lo = *(const bf16x4*)p;
    bf16x4 hi = *(const bf16x4*)(p + 4);
    bf16x8 r;
    r[0]=lo[0]; r[1]=lo[1]; r[2]=lo[2]; r[3]=lo[3];
    r[4]=hi[0]; r[5]=hi[1]; r[6]=hi[2]; r[7]=hi[3];
    return r;
}
__device__ inline void lds_store8(bf16* p, bf16x8 v) {
    bf16x4 lo, hi;
    lo[0]=v[0]; lo[1]=v[1]; lo[2]=v[2]; lo[3]=v[3];
    hi[0]=v[4]; hi[1]=v[5]; hi[2]=v[6]; hi[3]=v[7];
    *(bf16x4*)p = lo; *(bf16x4*)(p + 4) = hi;
}

// ---------------------------------------------------------------------------
// Embedding (f32 out)
// ---------------------------------------------------------------------------
__global__ void embed_kernel(const int* __restrict__ x,
                             const float* __restrict__ embed,
                             const float* __restrict__ pos,
                             float* __restrict__ h) {
    int token = blockIdx.x;
    int c = token % C;
    int id = x[token];
    const float* erow = embed + (size_t)id * E;
    const float* prow = pos   + (size_t)c  * E;
    float* hrow = h + (size_t)token * E;
    for (int e = threadIdx.x; e < E; e += blockDim.x)
        hrow[e] = erow[e] + prow[e];
}

// ---------------------------------------------------------------------------
// LayerNorm: f32 in -> bf16 out
// ---------------------------------------------------------------------------
__global__ void layernorm_kernel(const float* __restrict__ in,
                                 const float* __restrict__ w,
                                 const float* __restrict__ b,
                                 bf16* __restrict__ out) {
    __shared__ float red[256];
    int token = blockIdx.x;
    int tid = threadIdx.x;
    const float* row = in + (size_t)token * E;
    float x0 = row[tid];
    float x1 = row[tid + 256];
    float x2 = row[tid + 512];
    float x3 = row[tid + 768];

    red[tid] = x0 + x1 + x2 + x3;
    __syncthreads();
    for (int st = 128; st > 0; st >>= 1) {
        if (tid < st) red[tid] += red[tid + st];
        __syncthreads();
    }
    float mu = red[0] * (1.0f / E);
    __syncthreads();

    float d0 = x0 - mu, d1 = x1 - mu, d2 = x2 - mu, d3 = x3 - mu;
    red[tid] = d0 * d0 + d1 * d1 + d2 * d2 + d3 * d3;
    __syncthreads();
    for (int st = 128; st > 0; st >>= 1) {
        if (tid < st) red[tid] += red[tid + st];
        __syncthreads();
    }
    float var = red[0] * (1.0f / E);
    float inv = rsqrtf(var + EPS);

    bf16* orow = out + (size_t)token * E;
    orow[tid]       = __float2bfloat16(d0 * inv * w[tid]       + b[tid]);
    orow[tid + 256] = __float2bfloat16(d1 * inv * w[tid + 256] + b[tid + 256]);
    orow[tid + 512] = __float2bfloat16(d2 * inv * w[tid + 512] + b[tid + 512]);
    orow[tid + 768] = __float2bfloat16(d3 * inv * w[tid + 768] + b[tid + 768]);
}

// ---------------------------------------------------------------------------
// Weight convert+transpose: f32 [K,N] -> bf16 [N,K]
// ---------------------------------------------------------------------------
__global__ void transpose_bf16(const float* __restrict__ in,
                               bf16* __restrict__ out, int K, int Nn) {
    __shared__ float tile[32][33];
    int n0 = blockIdx.x * 32, k0 = blockIdx.y * 32;
    int tx = threadIdx.x & 31, ty = threadIdx.x >> 5;
    #pragma unroll
    for (int i = 0; i < 32; i += 8)
        tile[ty + i][tx] = in[(size_t)(k0 + ty + i) * Nn + n0 + tx];
    __syncthreads();
    #pragma unroll
    for (int i = 0; i < 32; i += 8)
        out[(size_t)(n0 + ty + i) * K + k0 + tx] = __float2bfloat16(tile[tx][ty + i]);
}

// ---------------------------------------------------------------------------
// V transpose: qkv bf16 [N,3E] (V part) -> vt bf16 [BH][D][C]
// ---------------------------------------------------------------------------
__global__ void transpose_v(const bf16* __restrict__ qkv,
                            bf16* __restrict__ vt) {
    __shared__ ushort tile[32][34];
    int c0 = blockIdx.x * 32;
    int d0 = (blockIdx.y & 1) * 32;
    int bh = blockIdx.y >> 1;
    int bb = bh >> 4, hh = bh & 15;
    int tx = threadIdx.x & 31, ty = threadIdx.x >> 5;
    const ushort* src = (const ushort*)qkv;
    ushort* dst = (ushort*)vt;
    #pragma unroll
    for (int i = 0; i < 32; i += 8)
        tile[ty + i][tx] = src[(size_t)(bb * C + c0 + ty + i) * E3 + 2 * E + hh * D + d0 + tx];
    __syncthreads();
    #pragma unroll
    for (int i = 0; i < 32; i += 8)
        dst[((size_t)bh * D + d0 + ty + i) * C + c0 + tx] = tile[tx][ty + i];
}

// ---------------------------------------------------------------------------
// bf16 MFMA GEMM (m97 structure) with XCD swizzle.
// C = [res +] ep(A @ Bt^T [+ bias]); A:[M,K] bf16, Bt:[Nc,K] bf16.
// ---------------------------------------------------------------------------
constexpr int GBM = 128, GBN = 128, GBK = 32;

__launch_bounds__(256)
__global__ void gemm_bf16(const bf16* __restrict__ A,
                          const bf16* __restrict__ Bt,
                          const float* __restrict__ bias,
                          const float* __restrict__ res,
                          float* __restrict__ outF,
                          bf16*  __restrict__ outB,
                          int M, int Nc, int K, int gelu_flag) {
    __shared__ __align__(16) bf16 As[GBM * GBK];
    __shared__ __align__(16) bf16 Bs[GBN * GBK];

    int tid  = threadIdx.x;
    int lane = tid & 63;
    int wid  = tid >> 6;
    int wr   = wid >> 1;
    int wc   = wid & 1;

    // XCD-aware swizzle (all grids here have nwg % 8 == 0)
    int nwg = gridDim.x * gridDim.y;
    int id  = blockIdx.y * gridDim.x + blockIdx.x;
    int cpx = nwg >> 3;
    int swz = (id & 7) * cpx + (id >> 3);
    int bx  = swz % gridDim.x;
    int by  = swz / gridDim.x;

    size_t brow = (size_t)by * GBM;
    size_t bcol = (size_t)bx * GBN;

    f32x4 acc[4][4] = {};

    for (int k0 = 0; k0 < K; k0 += GBK) {
        #pragma unroll
        for (int it = 0; it < 2; ++it) {
            int sbase = (wid * 2 + it) * 64;
            int s = sbase + lane;
            const bf16* ga = A  + (brow + (s >> 2)) * K + k0 + (s & 3) * 8;
            const bf16* gb = Bt + (bcol + (s >> 2)) * K + k0 + (s & 3) * 8;
            __builtin_amdgcn_global_load_lds(
                (const __attribute__((address_space(1))) void*)ga,
                (__attribute__((address_space(3))) void*)(As + (size_t)sbase * 8),
                16, 0, 0);
            __builtin_amdgcn_global_load_lds(
                (const __attribute__((address_space(1))) void*)gb,
                (__attribute__((address_space(3))) void*)(Bs + (size_t)sbase * 8),
                16, 0, 0);
        }
        __syncthreads();

        bf16x8 af[4], bfr[4];
        int klo = (lane >> 4) * 8;
        int rsub = lane & 15;
        #pragma unroll
        for (int m = 0; m < 4; ++m) {
            int row = wr * 64 + m * 16 + rsub;
            af[m] = *(const bf16x8*)(As + row * GBK + klo);
        }
        #pragma unroll
        for (int n = 0; n < 4; ++n) {
            int row = wc * 64 + n * 16 + rsub;
            bfr[n] = *(const bf16x8*)(Bs + row * GBK + klo);
        }
        #pragma unroll
        for (int m = 0; m < 4; ++m)
            #pragma unroll
            for (int n = 0; n < 4; ++n)
                acc[m][n] = __builtin_amdgcn_mfma_f32_16x16x32_bf16(
                    af[m], bfr[n], acc[m][n], 0, 0, 0);
        __syncthreads();
    }

    int crow = (lane >> 4) * 4;
    int ccol = lane & 15;
    #pragma unroll
    for (int m = 0; m < 4; ++m) {
        #pragma unroll
        for (int n = 0; n < 4; ++n) {
            #pragma unroll
            for (int r = 0; r < 4; ++r) {
                size_t row = brow + wr * 64 + m * 16 + crow + r;
                size_t col = bcol + wc * 64 + n * 16 + ccol;
                float val = acc[m][n][r];
                if (bias) val += bias[col];
                if (gelu_flag) val = 0.5f * val * (1.0f + erff(val * 0.70710678118f));
                if (res) val += res[row * Nc + col];
                if (outF) outF[row * Nc + col] = val;
                if (outB) outB[row * Nc + col] = __float2bfloat16(val);
            }
        }
    }
}

// ---------------------------------------------------------------------------
// Flash attention: block = (q-tile of 64, b*h). 4 waves, 16 q-rows each.
// qkv bf16 [N,3E]; vt bf16 [BH][D][C]; O bf16 [N,E].
// LDS tiles padded to stride 72 (2-way bank aliasing = free; 8B aligned).
// ---------------------------------------------------------------------------
constexpr int QBLK = 64;
constexpr int KVB  = 64;
constexpr int PSTR = 72;

__launch_bounds__(256)
__global__ void flash_attn(const bf16* __restrict__ qkv,
                           const bf16* __restrict__ vt,
                           bf16* __restrict__ O) {
    __shared__ bf16 sK[KVB][PSTR];
    __shared__ bf16 sV[D][PSTR];
    __shared__ bf16 sP[4][16][PSTR];

    int qt = blockIdx.x;
    int bh = blockIdx.y;
    int bb = bh >> 4, hh = bh & 15;
    int qbase = qt * QBLK;
    int tid = threadIdx.x, lane = tid & 63, w = tid >> 6;
    int l16 = lane & 15, lhi = lane >> 4;

    // Q fragments (row = l16, k-offset = lhi*8), kept in registers
    int qrow = qbase + w * 16 + l16;
    const bf16* qp = qkv + (size_t)(bb * C + qrow) * E3 + hh * D + lhi * 8;
    bf16x8 qf0 = *(const bf16x8*)qp;
    bf16x8 qf1 = *(const bf16x8*)(qp + 32);

    f32x4 oa[4] = {};
    float m_run[4] = {-INFINITY, -INFINITY, -INFINITY, -INFINITY};
    float l_run[4] = {0.f, 0.f, 0.f, 0.f};

    for (int t = 0; t <= qt; ++t) {
        int k0 = t * KVB;
        // ---- stage K and V^T tiles (reg -> padded LDS)
        #pragma unroll
        for (int it = 0; it < 2; ++it) {
            int s = it * 256 + tid;
            int row = s >> 3, c8 = s & 7;
            bf16x8 kv = *(const bf16x8*)(qkv + (size_t)(bb * C + k0 + row) * E3 + E + hh * D + c8 * 8);
            lds_store8(&sK[row][c8 * 8], kv);
            bf16x8 vv = *(const bf16x8*)(vt + ((size_t)bh * D + row) * C + k0 + c8 * 8);
            lds_store8(&sV[row][c8 * 8], vv);
        }
        __syncthreads();

        // ---- S = Q @ K^T for this wave's 16 q-rows x 64 k-cols
        f32x4 sc[4] = {};
        #pragma unroll
        for (int n = 0; n < 4; ++n) {
            bf16x8 kf0 = lds_load8(&sK[n * 16 + l16][lhi * 8]);
            sc[n] = __builtin_amdgcn_mfma_f32_16x16x32_bf16(qf0, kf0, sc[n], 0, 0, 0);
            bf16x8 kf1 = lds_load8(&sK[n * 16 + l16][32 + lhi * 8]);
            sc[n] = __builtin_amdgcn_mfma_f32_16x16x32_bf16(qf1, kf1, sc[n], 0, 0, 0);
        }

        // ---- scale + causal mask (diagonal tile only)
        int qg = qbase + w * 16 + lhi * 4;
        #pragma unroll
        for (int n = 0; n < 4; ++n) {
            int kg = k0 + n * 16 + l16;
            #pragma unroll
            for (int r = 0; r < 4; ++r) {
                float vvv = sc[n][r] * 0.125f;
                if (t == qt && kg > qg + r) vvv = -1e30f;
                sc[n][r] = vvv;
            }
        }

        // ---- online softmax (row state lives in 16-lane group)
        float pm[4];
        #pragma unroll
        for (int r = 0; r < 4; ++r)
            pm[r] = fmaxf(fmaxf(sc[0][r], sc[1][r]), fmaxf(sc[2][r], sc[3][r]));
        #pragma unroll
        for (int xm = 1; xm <= 8; xm <<= 1)
            #pragma unroll
            for (int r = 0; r < 4; ++r)
                pm[r] = fmaxf(pm[r], __shfl_xor(pm[r], xm));

        float corr[4];
        #pragma unroll
        for (int r = 0; r < 4; ++r) {
            float mn = fmaxf(m_run[r], pm[r]);
            corr[r] = __expf(m_run[r] - mn);
            m_run[r] = mn;
        }
        f32x4 p[4];
        #pragma unroll
        for (int n = 0; n < 4; ++n)
            #pragma unroll
            for (int r = 0; r < 4; ++r)
                p[n][r] = __expf(sc[n][r] - m_run[r]);

        float rsum[4];
        #pragma unroll
        for (int r = 0; r < 4; ++r)
            rsum[r] = p[0][r] + p[1][r] + p[2][r] + p[3][r];
        #pragma unroll
        for (int xm = 1; xm <= 8; xm <<= 1)
            #pragma unroll
            for (int r = 0; r < 4; ++r)
                rsum[r] += __shfl_xor(rsum[r], xm);
        #pragma unroll
        for (int r = 0; r < 4; ++r)
            l_run[r] = l_run[r] * corr[r] + rsum[r];
        #pragma unroll
        for (int nd = 0; nd < 4; ++nd)
            #pragma unroll
            for (int r = 0; r < 4; ++r)
                oa[nd][r] *= corr[r];

        // ---- P -> per-wave LDS (C-layout) -> A-frag layout
        #pragma unroll
        for (int n = 0; n < 4; ++n)
            #pragma unroll
            for (int r = 0; r < 4; ++r)
                sP[w][lhi * 4 + r][n * 16 + l16] = __float2bfloat16(p[n][r]);
        // same-wave RAW: compiler inserts lgkmcnt wait; no barrier needed
        bf16x8 pa0 = lds_load8(&sP[w][l16][lhi * 8]);
        bf16x8 pa1 = lds_load8(&sP[w][l16][32 + lhi * 8]);

        // ---- O += P @ V   (B-operand rows = d, from V^T tile)
        #pragma unroll
        for (int nd = 0; nd < 4; ++nd) {
            bf16x8 vf0 = lds_load8(&sV[nd * 16 + l16][lhi * 8]);
            oa[nd] = __builtin_amdgcn_mfma_f32_16x16x32_bf16(pa0, vf0, oa[nd], 0, 0, 0);
            bf16x8 vf1 = lds_load8(&sV[nd * 16 + l16][32 + lhi * 8]);
            oa[nd] = __builtin_amdgcn_mfma_f32_16x16x32_bf16(pa1, vf1, oa[nd], 0, 0, 0);
        }
        __syncthreads();
    }

    // ---- epilogue: O row = qbase + w*16 + lhi*4 + r, col = nd*16 + l16
    #pragma unroll
    for (int r = 0; r < 4; ++r) {
        float inv = 1.0f / l_run[r];
        int qg = qbase + w * 16 + lhi * 4 + r;
        bf16* orow = O + (size_t)(bb * C + qg) * E + hh * D;
        #pragma unroll
        for (int nd = 0; nd < 4; ++nd)
            orow[nd * 16 + l16] = __float2bfloat16(oa[nd][r] * inv);
    }
}

// ---------------------------------------------------------------------------
extern "C" void kernel_launch(void* const* d_in, const int* in_sizes, int n_in,
                              void* d_out, int out_size, void* d_ws, size_t ws_size,
                              hipStream_t stream) {
    const int*   x     = (const int*)  d_in[0];
    const float* embed = (const float*)d_in[1];
    const float* pos   = (const float*)d_in[2];
    const float* Wq    = (const float*)d_in[3];
    const float* Wk    = (const float*)d_in[4];
    const float* Wv    = (const float*)d_in[5];
    const float* Wo    = (const float*)d_in[6];
    const float* ln1w  = (const float*)d_in[7];
    const float* ln1b  = (const float*)d_in[8];
    const float* ln2w  = (const float*)d_in[9];
    const float* ln2b  = (const float*)d_in[10];
    const float* W1    = (const float*)d_in[11];
    const float* b1    = (const float*)d_in[12];
    const float* W2    = (const float*)d_in[13];
    const float* b2    = (const float*)d_in[14];
    const float* lnfw  = (const float*)d_in[15];
    const float* lnfb  = (const float*)d_in[16];
    const float* Wout  = (const float*)d_in[17];
    const float* bout  = (const float*)d_in[18];
    float* out = (float*)d_out;

    char* p = (char*)d_ws;
    auto alloc = [&](size_t bytes) {
        char* r = p;
        p += (bytes + 255) & ~(size_t)255;
        return r;
    };
    float* h    = (float*)alloc((size_t)N * E  * 4);
    bf16*  qkvb = (bf16*) alloc((size_t)N * E3 * 2);
    bf16*  hn   = (bf16*) alloc((size_t)N * E  * 2);
    bf16*  attn = (bf16*) alloc((size_t)N * E  * 2);
    bf16*  ff   = (bf16*) alloc((size_t)N * FF * 2);
    bf16*  vt   = (bf16*) alloc((size_t)B * H * D * C * 2);
    bf16*  qkvt = (bf16*) alloc((size_t)L * E3 * E * 2);
    bf16*  wot  = (bf16*) alloc((size_t)L * E  * E * 2);
    bf16*  w1t  = (bf16*) alloc((size_t)L * FF * E * 2);
    bf16*  w2t  = (bf16*) alloc((size_t)L * E  * FF * 2);
    bf16*  wvt  = (bf16*) alloc((size_t)V * E  * 2);

    for (int i = 0; i < L; ++i) {
        transpose_bf16<<<dim3(E / 32, E / 32), 256, 0, stream>>>(
            Wq + (size_t)i * E * E, qkvt + ((size_t)i * E3 + 0 * E) * E, E, E);
        transpose_bf16<<<dim3(E / 32, E / 32), 256, 0, stream>>>(
            Wk + (size_t)i * E * E, qkvt + ((size_t)i * E3 + 1 * E) * E, E, E);
        transpose_bf16<<<dim3(E / 32, E / 32), 256, 0, stream>>>(
            Wv + (size_t)i * E * E, qkvt + ((size_t)i * E3 + 2 * E) * E, E, E);
        transpose_bf16<<<dim3(E / 32, E / 32), 256, 0, stream>>>(
            Wo + (size_t)i * E * E, wot + (size_t)i * E * E, E, E);
        transpose_bf16<<<dim3(FF / 32, E / 32), 256, 0, stream>>>(
            W1 + (size_t)i * E * FF, w1t + (size_t)i * FF * E, E, FF);
        transpose_bf16<<<dim3(E / 32, FF / 32), 256, 0, stream>>>(
            W2 + (size_t)i * FF * E, w2t + (size_t)i * E * FF, FF, E);
    }
    transpose_bf16<<<dim3(V / 32, E / 32), 256, 0, stream>>>(Wout, wvt, E, V);

    embed_kernel<<<N, 256, 0, stream>>>(x, embed, pos, h);

    dim3 gQKV(E3 / GBN, N / GBM);   // 384 blocks
    dim3 gE  (E  / GBN, N / GBM);   // 128
    dim3 gF  (FF / GBN, N / GBM);   // 512
    dim3 gV  (V  / GBN, N / GBM);   // 4000

    for (int i = 0; i < L; ++i) {
        layernorm_kernel<<<N, 256, 0, stream>>>(h, ln1w + i * E, ln1b + i * E, hn);

        // packed QKV (bf16 out)
        gemm_bf16<<<gQKV, 256, 0, stream>>>(hn, qkvt + (size_t)i * E3 * E,
                                            nullptr, nullptr, nullptr, qkvb,
                                            N, E3, E, 0);

        transpose_v<<<dim3(C / 32, 2 * B * H), 256, 0, stream>>>(qkvb, vt);

        flash_attn<<<dim3(C / QBLK, B * H), 256, 0, stream>>>(qkvb, vt, attn);

        // h = h + attn @ Wo
        gemm_bf16<<<gE, 256, 0, stream>>>(attn, wot + (size_t)i * E * E,
                                          nullptr, h, h, nullptr,
                                          N, E, E, 0);

        layernorm_kernel<<<N, 256, 0, stream>>>(h, ln2w + i * E, ln2b + i * E, hn);

        // ff = gelu(hn @ W1 + b1)
        gemm_bf16<<<gF, 256, 0, stream>>>(hn, w1t + (size_t)i * FF * E,
                                          b1 + (size_t)i * FF, nullptr,
                                          nullptr, ff,
                                          N, FF, E, 1);
        // h = h + ff @ W2 + b2
        gemm_bf16<<<gE, 256, 0, stream>>>(ff, w2t + (size_t)i * E * FF,
                                          b2 + (size_t)i * E, h, h, nullptr,
                                          N, E, FF, 0);
    }

    layernorm_kernel<<<N, 256, 0, stream>>>(h, lnfw, lnfb, hn);
    gemm_bf16<<<gV, 256, 0, stream>>>(hn, wvt, bout, nullptr, out, nullptr,
                                      N, V, E, 0);
}